// Round 19
// baseline (578.524 us; speedup 1.0000x reference)
//
#include <hip/hip_runtime.h>
#include <hip/hip_bf16.h>
#include <cstdint>

typedef __bf16 bf16;
typedef __bf16 bf16x8 __attribute__((ext_vector_type(8)));
typedef __bf16 bf16x4 __attribute__((ext_vector_type(4)));
typedef float  f32x4  __attribute__((ext_vector_type(4)));

constexpr int V_    = 32000;
constexpr int SMAX_ = 1024;
constexpr int D_    = 1024;
constexpr int H_    = 16;
constexpr int L_    = 2;
constexpr int DFF_  = 4096;
constexpr int WIN_  = 256;
constexpr int B_    = 2;
constexpr int M_    = B_ * SMAX_; // 2048

#define SBAR0_() __builtin_amdgcn_sched_barrier(0)
#define HWBAR_() { __builtin_amdgcn_s_barrier(); SBAR0_(); }
#define LGKM0_() { asm volatile("s_waitcnt lgkmcnt(0)" ::: "memory"); SBAR0_(); }
#define VM0_()   { asm volatile("s_waitcnt vmcnt(0)" ::: "memory"); SBAR0_(); }
#define VM8_()   { asm volatile("s_waitcnt vmcnt(8)" ::: "memory"); SBAR0_(); }

// ---------------------------------------------------------------------------
// Aux work: prep chunks attached as extra grid blocks to underfilled
// dispatches (R17/R18, passing). kind: -1 none, 0 qkv/wo transposes + pack,
// 1 w1 transpose, 2 w2 transpose, 3 emb f32->bf16 rows [base, base+count).
// ---------------------------------------------------------------------------
struct AuxArgs {
  const float *wq, *wk, *wv, *wo, *w1, *w2, *emb, *bq, *bk, *bv;
  bf16 *wqkv_t, *wo_t, *w1_t, *w2_t, *emb_bf;
  float *bqkv;
  int kind;
  int base;
};

__device__ __forceinline__ void aux_transpose(
    const float* src, bf16* dst, int Kk, int Nn, int tid, int t)
{
  __shared__ float tile[32][33];
  const int tx = t & 31, ty = t >> 5;
  int tilesX = Nn >> 5;
  int n0 = (tid % tilesX) << 5, k0 = (tid / tilesX) << 5;
  #pragma unroll
  for (int i = 0; i < 4; i++)
    tile[ty + i * 8][tx] = src[(long)(k0 + ty + i * 8) * Nn + n0 + tx];
  __syncthreads();
  #pragma unroll
  for (int i = 0; i < 4; i++)
    dst[(long)(n0 + ty + i * 8) * Kk + k0 + tx] = (bf16)tile[tx][ty + i * 8];
}

__device__ __forceinline__ void aux_do(const AuxArgs& A, int b, int t)
{
  if (A.kind == 0) {
    if (b < 8192) {                 // wq/wk/wv/wo: 4 mats x 2L x 1024 tiles
      int mat = b >> 11, r = b & 2047, z = r >> 10, tid = r & 1023;
      const float* s; bf16* d;
      if (mat == 0)      { s = A.wq + (long)z * 1048576; d = A.wqkv_t + (long)z * 3145728; }
      else if (mat == 1) { s = A.wk + (long)z * 1048576; d = A.wqkv_t + (long)z * 3145728 + 1048576; }
      else if (mat == 2) { s = A.wv + (long)z * 1048576; d = A.wqkv_t + (long)z * 3145728 + 2097152; }
      else               { s = A.wo + (long)z * 1048576; d = A.wo_t   + (long)z * 1048576; }
      aux_transpose(s, d, 1024, 1024, tid, t);
    } else {                        // pack bqkv (24 blocks)
      int i = (b - 8192) * 256 + t;
      if (i < L_ * 3072) {
        int l = i / 3072, c = i % 3072;
        float v = (c < 1024) ? A.bq[l * 1024 + c]
                : (c < 2048) ? A.bk[l * 1024 + c - 1024]
                             : A.bv[l * 1024 + c - 2048];
        A.bqkv[i] = v;
      }
    }
  } else if (A.kind == 1) {         // w1: 2L x 4096 tiles
    int z = b >> 12, tid = b & 4095;
    aux_transpose(A.w1 + (long)z * 4194304, A.w1_t + (long)z * 4194304, 1024, 4096, tid, t);
  } else if (A.kind == 2) {         // w2: 2L x 4096 tiles
    int z = b >> 12, tid = b & 4095;
    aux_transpose(A.w2 + (long)z * 4194304, A.w2_t + (long)z * 4194304, 4096, 1024, tid, t);
  } else if (A.kind == 3) {         // emb cvt rows
    long i = (long)(A.base + b) * 256 + t;
    float4 v = ((const float4*)A.emb)[i];
    bf16x4 o; o[0] = (bf16)v.x; o[1] = (bf16)v.y; o[2] = (bf16)v.z; o[3] = (bf16)v.w;
    ((bf16x4*)A.emb_bf)[i] = o;
  }
}

// ---------------------------------------------------------------------------
// LM head (R15-18, passing): 256x256, 8 waves (2Mx4N, wave 128x64), BK=32,
// 4 LDS buffers, depth-3 counted pipeline (vmcnt(8), one barrier/iter,
// 32 MFMA per sync), swapped-operand MFMA, f32x4 temporal epilogue.
// ---------------------------------------------------------------------------
__global__ __launch_bounds__(512, 1) void gemm_lmA(
    const bf16* __restrict__ A, const bf16* __restrict__ BT,
    float* __restrict__ outf, int Nn)
{
  constexpr int KK = 1024, NT = KK / 32;
  __shared__ __align__(16) bf16 ldsA[4 * 8192];   // 4 bufs x 256 rows x 32
  __shared__ __align__(16) bf16 ldsB[4 * 8192];

  const int t = threadIdx.x, lane = t & 63, w = t >> 6;
  const int l16 = lane & 15, lh = lane >> 4;
  const int wm = w >> 2, wn = w & 3;              // 2M x 4N, wave 128x64

  const int nloc = gridDim.x >> 3;                // 1000/8 = 125
  const int wg = (blockIdx.x & 7) * nloc + (blockIdx.x >> 3);
  const long m0 = (long)(wg & 7) * 256;
  const long n0 = (long)(wg >> 3) * 256;

  auto STG = [&](const bf16* src, long rowBase, bf16* dst, int k0) {
    #pragma unroll
    for (int j = 0; j < 2; ++j) {
      int p = j * 8192 + t * 16;
      int row = p >> 6;
      int sl = ((p >> 4) & 3) ^ (row & 3);
      const bf16* g = src + (rowBase + row) * (long)KK + k0 + sl * 8;
      __builtin_amdgcn_global_load_lds(
          (const __attribute__((address_space(1))) uint32_t*)g,
          (__attribute__((address_space(3))) uint32_t*)(dst + j * 4096 + w * 512),
          16, 0, 0);
    }
  };
  auto LDF = [&](const bf16* base, int rowb) -> bf16x8 {
    int row = rowb + l16;
    return *(const bf16x8*)(base + row * 32 + ((lh ^ (l16 & 3)) << 3));
  };

  f32x4 acc[8][4] = {};

  STG(A, m0, ldsA,          0);  STG(BT, n0, ldsB,          0);
  STG(A, m0, ldsA + 8192,  32);  STG(BT, n0, ldsB + 8192,  32);
  STG(A, m0, ldsA + 16384, 64);  STG(BT, n0, ldsB + 16384, 64);
  int kNext = 96;

  for (int i = 0; i < NT; ++i) {
    const int cur = i & 3, nb = (i + 3) & 3;
    VM8_();
    HWBAR_();
    const bf16* Ac = ldsA + cur * 8192;
    const bf16* Bc = ldsB + cur * 8192;
    bf16x8 af[8], bb[4];
    #pragma unroll
    for (int mi = 0; mi < 8; ++mi) af[mi] = LDF(Ac, wm * 128 + mi * 16);
    #pragma unroll
    for (int ni = 0; ni < 4; ++ni) bb[ni] = LDF(Bc, wn * 64 + ni * 16);
    STG(A, m0, ldsA + nb * 8192, kNext);
    STG(BT, n0, ldsB + nb * 8192, kNext);
    kNext += 32; if (kNext == KK) kNext = 0;
    LGKM0_();
    __builtin_amdgcn_s_setprio(1);
    #pragma unroll
    for (int mi = 0; mi < 8; ++mi)
      #pragma unroll
      for (int ni = 0; ni < 4; ++ni)
        acc[mi][ni] = __builtin_amdgcn_mfma_f32_16x16x32_bf16(bb[ni], af[mi], acc[mi][ni], 0, 0, 0);
    __builtin_amdgcn_s_setprio(0);
  }

  asm volatile("s_waitcnt vmcnt(0) lgkmcnt(0)" ::: "memory");
  #pragma unroll
  for (int mi = 0; mi < 8; ++mi) {
    long row = m0 + wm * 128 + mi * 16 + l16;
    #pragma unroll
    for (int ni = 0; ni < 4; ++ni) {
      long col = n0 + wn * 64 + ni * 16 + lh * 4;
      *(f32x4*)(outf + row * Nn + col) = acc[mi][ni];
    }
  }
}

// ---------------------------------------------------------------------------
// Layer GEMMs (R18 template, passing): BM/BN-templated, drain sync,
// swapped-operand MFMA, vectorized epilogues, optional aux tail.
// EPI: 0 bias->bf16, 1 bias+gelu->bf16, 2 bias+residual->f32, 3 ->f32
// ---------------------------------------------------------------------------
template<int BM, int BN, int EPI>
__global__ __launch_bounds__(256) void gemm_l2(
    const bf16* __restrict__ A, const bf16* __restrict__ BT,
    const float* __restrict__ bias, float* __restrict__ resid,
    bf16* __restrict__ outb, float* __restrict__ outf,
    int Nn, int Kk, int nbyMask, int nbyShift,
    AuxArgs aux, int mainBlocks)
{
  if ((int)blockIdx.x >= mainBlocks) {
    aux_do(aux, (int)blockIdx.x - mainBlocks, threadIdx.x);
    return;
  }
  constexpr int MR = BM / 32;
  constexpr int NR = BN / 32;
  constexpr int CA = BM / 32;
  constexpr int CB = BN / 32;
  __shared__ __align__(16) bf16 ldsA[2][BM * 64];
  __shared__ __align__(16) bf16 ldsB[2][BN * 64];

  const int t = threadIdx.x, lane = t & 63, w = t >> 6;
  const int l16 = lane & 15, lh = lane >> 4;
  const int wm = w >> 1, wn = w & 1;

  const int nwg = mainBlocks, bid = blockIdx.x;
  const int nloc = nwg >> 3;
  const int wg = (bid & 7) * nloc + (bid >> 3);
  const long m0 = (long)(wg & nbyMask) * BM;
  const long n0 = (long)(wg >> nbyShift) * BN;

  auto STGA = [&](int c, int k0) {
    #pragma unroll
    for (int q = 0; q < CA; ++q) {
      int row = q * 32 + (t >> 3);
      int sl  = (t & 7) ^ (row & 7);
      const bf16* g = A + (m0 + row) * (long)Kk + k0 + sl * 8;
      __builtin_amdgcn_global_load_lds(
          (const __attribute__((address_space(1))) uint32_t*)g,
          (__attribute__((address_space(3))) uint32_t*)(&ldsA[c][q * 2048 + t * 8]),
          16, 0, 0);
    }
  };
  auto STGB = [&](int c, int k0) {
    #pragma unroll
    for (int q = 0; q < CB; ++q) {
      int row = q * 32 + (t >> 3);
      int sl  = (t & 7) ^ (row & 7);
      const bf16* g = BT + (n0 + row) * (long)Kk + k0 + sl * 8;
      __builtin_amdgcn_global_load_lds(
          (const __attribute__((address_space(1))) uint32_t*)g,
          (__attribute__((address_space(3))) uint32_t*)(&ldsB[c][q * 2048 + t * 8]),
          16, 0, 0);
    }
  };
  auto LDA = [&](int c, int mi, int ks) -> bf16x8 {
    int row = wm * (BM / 2) + mi * 16 + l16;
    int sl  = (ks * 4 + lh) ^ (row & 7);
    return *(const bf16x8*)(&ldsA[c][row * 64 + sl * 8]);
  };
  auto LDB = [&](int c, int ni, int ks) -> bf16x8 {
    int row = wn * (BN / 2) + ni * 16 + l16;
    int sl  = (ks * 4 + lh) ^ (row & 7);
    return *(const bf16x8*)(&ldsB[c][row * 64 + sl * 8]);
  };

  f32x4 acc[MR][NR] = {};
  bf16x8 a[MR], b[NR];

  STGA(0, 0); STGB(0, 0);
  int kNext = 64;

  const int NT = Kk >> 6;
  for (int j = 0; j < NT; ++j) {
    const int c = j & 1;
    VM0_();
    HWBAR_();
    #pragma unroll
    for (int mi = 0; mi < MR; ++mi) a[mi] = LDA(c, mi, 0);
    #pragma unroll
    for (int ni = 0; ni < NR; ++ni) b[ni] = LDB(c, ni, 0);
    STGA(c ^ 1, kNext); STGB(c ^ 1, kNext);
    LGKM0_();
    __builtin_amdgcn_s_setprio(1);
    #pragma unroll
    for (int mi = 0; mi < MR; ++mi)
      #pragma unroll
      for (int ni = 0; ni < NR; ++ni)
        acc[mi][ni] = __builtin_amdgcn_mfma_f32_16x16x32_bf16(b[ni], a[mi], acc[mi][ni], 0, 0, 0);
    __builtin_amdgcn_s_setprio(0);
    HWBAR_();
    #pragma unroll
    for (int mi = 0; mi < MR; ++mi) a[mi] = LDA(c, mi, 1);
    #pragma unroll
    for (int ni = 0; ni < NR; ++ni) b[ni] = LDB(c, ni, 1);
    LGKM0_();
    __builtin_amdgcn_s_setprio(1);
    #pragma unroll
    for (int mi = 0; mi < MR; ++mi)
      #pragma unroll
      for (int ni = 0; ni < NR; ++ni)
        acc[mi][ni] = __builtin_amdgcn_mfma_f32_16x16x32_bf16(b[ni], a[mi], acc[mi][ni], 0, 0, 0);
    __builtin_amdgcn_s_setprio(0);
    kNext += 64; if (kNext == Kk) kNext = 0;
  }

  // swapped D: row = m (lane&15), col = n (lh*4 + reg)
  #pragma unroll
  for (int mi = 0; mi < MR; ++mi) {
    long row = m0 + wm * (BM / 2) + mi * 16 + l16;
    #pragma unroll
    for (int ni = 0; ni < NR; ++ni) {
      long col = n0 + wn * (BN / 2) + ni * 16 + lh * 4;
      f32x4 v = acc[mi][ni];
      if (EPI == 3) {
        *(f32x4*)(outf + row * Nn + col) = v;
      } else {
        f32x4 bv = *(const f32x4*)(bias + col);
        v += bv;
        if (EPI == 0) {
          bf16x4 o;
          #pragma unroll
          for (int e = 0; e < 4; ++e) o[e] = (bf16)v[e];
          *(bf16x4*)(outb + row * Nn + col) = o;
        } else if (EPI == 1) {
          bf16x4 o;
          #pragma unroll
          for (int e = 0; e < 4; ++e) {
            float xx = v[e];
            o[e] = (bf16)(0.5f * xx * (1.0f + erff(xx * 0.70710678118654752f)));
          }
          *(bf16x4*)(outb + row * Nn + col) = o;
        } else { // EPI == 2
          f32x4 r = *(f32x4*)(resid + row * Nn + col);
          r += v;
          *(f32x4*)(resid + row * Nn + col) = r;
        }
      }
    }
  }
}

// ---------------------------------------------------------------------------
// Sliding-window causal flash attention (passing) + optional aux tail.
// ---------------------------------------------------------------------------
__global__ __launch_bounds__(256) void attn_swa(
    const bf16* __restrict__ qkv, bf16* __restrict__ o,
    AuxArgs aux, int mainBlocks)
{
  if ((int)blockIdx.x >= mainBlocks) {
    aux_do(aux, (int)blockIdx.x - mainBlocks, threadIdx.x);
    return;
  }
  constexpr int PADK = 72;
  constexpr int PADV = 40;
  __shared__ bf16 Qs[64 * PADK];
  __shared__ bf16 Ks[32 * PADK];
  __shared__ bf16 Vt[64 * PADV];
  __shared__ bf16 Ps[4][16 * PADV];

  const int bid = blockIdx.x;
  const int qb = bid & 15;
  const int h  = (bid >> 4) & 15;
  const int b  = bid >> 8;
  const int q0 = qb * 64;
  const int t = threadIdx.x, lane = t & 63, w = t >> 6;
  const int l16 = lane & 15, lh = lane >> 4;

  #pragma unroll
  for (int i = 0; i < 2; i++) {
    int e = t + i * 256;
    int row = e >> 3, cc = e & 7;
    uint4 g = *(const uint4*)(qkv + ((long)(b * SMAX_ + q0 + row)) * 3072 + h * 64 + cc * 8);
    *(uint4*)(Qs + row * PADK + cc * 8) = g;
  }
  __syncthreads();
  bf16x8 aq[2];
  const int qrow = w * 16 + l16;
  #pragma unroll
  for (int ks = 0; ks < 2; ks++)
    aq[ks] = *(const bf16x8*)(Qs + qrow * PADK + ks * 32 + lh * 8);

  float m_run[4], l_run[4];
  f32x4 oacc[4];
  #pragma unroll
  for (int rr = 0; rr < 4; rr++) { m_run[rr] = -1e30f; l_run[rr] = 0.0f; }
  #pragma unroll
  for (int n = 0; n < 4; n++) oacc[n] = (f32x4){0.f, 0.f, 0.f, 0.f};

  const int tlo = q0 - (WIN_ - 1);
  const int jlo = (tlo <= 0) ? 0 : (tlo & ~31);
  const int iq  = q0 + w * 16 + lh * 4;

  for (int j0 = jlo; j0 < q0 + 64; j0 += 32) {
    __syncthreads();
    {
      int row = t >> 3, cc = t & 7;
      long base = ((long)(b * SMAX_ + j0 + row)) * 3072 + h * 64 + cc * 8;
      uint4 gk = *(const uint4*)(qkv + base + 1024);
      *(uint4*)(Ks + row * PADK + cc * 8) = gk;
      bf16x8 vv = *(const bf16x8*)(qkv + base + 2048);
      #pragma unroll
      for (int j = 0; j < 8; j++)
        Vt[(cc * 8 + j) * PADV + row] = vv[j];
    }
    __syncthreads();

    f32x4 s[2] = {(f32x4){0.f,0.f,0.f,0.f}, (f32x4){0.f,0.f,0.f,0.f}};
    #pragma unroll
    for (int nt = 0; nt < 2; nt++)
      #pragma unroll
      for (int ks = 0; ks < 2; ks++) {
        bf16x8 bk = *(const bf16x8*)(Ks + (nt * 16 + l16) * PADK + ks * 32 + lh * 8);
        s[nt] = __builtin_amdgcn_mfma_f32_16x16x32_bf16(aq[ks], bk, s[nt], 0, 0, 0);
      }

    float sc[2][4];
    #pragma unroll
    for (int nt = 0; nt < 2; nt++)
      #pragma unroll
      for (int rr = 0; rr < 4; rr++) {
        int i = iq + rr;
        int j = j0 + nt * 16 + l16;
        float v = s[nt][rr] * 0.125f;
        bool ok = (j <= i) && (i - j < WIN_);
        sc[nt][rr] = ok ? v : -1e30f;
      }

    float pb[2][4], alpha[4];
    #pragma unroll
    for (int rr = 0; rr < 4; rr++) {
      float mt = fmaxf(sc[0][rr], sc[1][rr]);
      #pragma unroll
      for (int off = 1; off < 16; off <<= 1) mt = fmaxf(mt, __shfl_xor(mt, off, 64));
      float mn = fmaxf(m_run[rr], mt);
      float a = __expf(m_run[rr] - mn);
      m_run[rr] = mn; alpha[rr] = a;
      float p0 = __expf(sc[0][rr] - mn);
      float p1 = __expf(sc[1][rr] - mn);
      pb[0][rr] = p0; pb[1][rr] = p1;
      float ls = p0 + p1;
      #pragma unroll
      for (int off = 1; off < 16; off <<= 1) ls += __shfl_xor(ls, off, 64);
      l_run[rr] = l_run[rr] * a + ls;
    }
    #pragma unroll
    for (int n = 0; n < 4; n++)
      #pragma unroll
      for (int rr = 0; rr < 4; rr++) oacc[n][rr] *= alpha[rr];

    #pragma unroll
    for (int rr = 0; rr < 4; rr++) {
      int prow = lh * 4 + rr;
      Ps[w][prow * PADV + l16]      = (bf16)pb[0][rr];
      Ps[w][prow * PADV + 16 + l16] = (bf16)pb[1][rr];
    }
    __syncthreads();

    bf16x8 pa = *(const bf16x8*)(&Ps[w][l16 * PADV + lh * 8]);
    #pragma unroll
    for (int n = 0; n < 4; n++) {
      bf16x8 bv = *(const bf16x8*)(Vt + (n * 16 + l16) * PADV + lh * 8);
      oacc[n] = __builtin_amdgcn_mfma_f32_16x16x32_bf16(pa, bv, oacc[n], 0, 0, 0);
    }
  }

  #pragma unroll
  for (int rr = 0; rr < 4; rr++) {
    int i = iq + rr;
    float inv = 1.0f / l_run[rr];
    #pragma unroll
    for (int n = 0; n < 4; n++)
      o[((long)(b * SMAX_ + i)) * D_ + h * 64 + n * 16 + l16] = (bf16)(oacc[n][rr] * inv);
  }
}

// ---------------------------------------------------------------------------
__global__ __launch_bounds__(256) void embed_k(
    const int* __restrict__ ids, const float* __restrict__ emb,
    const float* __restrict__ pos, float* __restrict__ x)
{
  const int m = blockIdx.x, t = threadIdx.x;
  const int id = ids[m];
  const int s = m & (SMAX_ - 1);
  float4 e = ((const float4*)(emb + (long)id * D_))[t];
  float4 p = ((const float4*)(pos + (long)s * D_))[t];
  float4 rr; rr.x = e.x + p.x; rr.y = e.y + p.y; rr.z = e.z + p.z; rr.w = e.w + p.w;
  ((float4*)(x + (long)m * D_))[t] = rr;
}

__global__ __launch_bounds__(256) void rmsnorm_k(
    const float* __restrict__ x, const float* __restrict__ wgt,
    bf16* __restrict__ out, AuxArgs aux, int mainBlocks)
{
  if ((int)blockIdx.x >= mainBlocks) {
    aux_do(aux, (int)blockIdx.x - mainBlocks, threadIdx.x);
    return;
  }
  __shared__ float red[4];
  const int m = blockIdx.x, t = threadIdx.x;
  float4 v = ((const float4*)(x + (long)m * D_))[t];
  float ss = v.x * v.x + v.y * v.y + v.z * v.z + v.w * v.w;
  #pragma unroll
  for (int off = 1; off < 64; off <<= 1) ss += __shfl_xor(ss, off, 64);
  const int lane = t & 63, w = t >> 6;
  if (lane == 0) red[w] = ss;
  __syncthreads();
  float tot = red[0] + red[1] + red[2] + red[3];
  float rs = rsqrtf(tot * (1.0f / D_) + 1e-6f);
  float4 g = ((const float4*)wgt)[t];
  bf16x4 o;
  o[0] = (bf16)(v.x * rs * g.x); o[1] = (bf16)(v.y * rs * g.y);
  o[2] = (bf16)(v.z * rs * g.z); o[3] = (bf16)(v.w * rs * g.w);
  ((bf16x4*)(out + (long)m * D_))[t] = o;
}

// ---------------------------------------------------------------------------
extern "C" void kernel_launch(void* const* d_in, const int* in_sizes, int n_in,
                              void* d_out, int out_size, void* d_ws, size_t ws_size,
                              hipStream_t stream)
{
  const int*   ids = (const int*)d_in[0];
  const float* emb = (const float*)d_in[1];
  const float* pos = (const float*)d_in[2];
  const float* n1w = (const float*)d_in[3];
  const float* n2w = (const float*)d_in[4];
  const float* wq  = (const float*)d_in[5];
  const float* bq  = (const float*)d_in[6];
  const float* wk  = (const float*)d_in[7];
  const float* bk  = (const float*)d_in[8];
  const float* wv  = (const float*)d_in[9];
  const float* bv  = (const float*)d_in[10];
  const float* wo  = (const float*)d_in[11];
  const float* bo  = (const float*)d_in[12];
  const float* w1  = (const float*)d_in[13];
  const float* b1  = (const float*)d_in[14];
  const float* w2  = (const float*)d_in[15];
  const float* b2  = (const float*)d_in[16];
  const float* nfw = (const float*)d_in[17];

  char* p = (char*)d_ws;
  auto alloc = [&](size_t bytes) {
    char* rr = p; p += (bytes + 255) & ~(size_t)255; return rr;
  };
  bf16*  wqkv_t = (bf16*) alloc((size_t)L_ * 3 * 1024 * 1024 * 2);
  bf16*  wo_t   = (bf16*) alloc((size_t)L_ * 1024 * 1024 * 2);
  bf16*  w1_t   = (bf16*) alloc((size_t)L_ * 4096 * 1024 * 2);
  bf16*  w2_t   = (bf16*) alloc((size_t)L_ * 1024 * 4096 * 2);
  bf16*  emb_bf = (bf16*) alloc((size_t)V_ * D_ * 2);
  float* bqkv   = (float*)alloc((size_t)L_ * 3072 * 4);
  float* x      = (float*)alloc((size_t)M_ * D_ * 4);
  bf16*  hbuf   = (bf16*) alloc((size_t)M_ * D_ * 2);
  bf16*  qkv    = (bf16*) alloc((size_t)M_ * 3072 * 2);
  bf16*  obuf   = (bf16*) alloc((size_t)M_ * D_ * 2);
  bf16*  ff     = (bf16*) alloc((size_t)M_ * DFF_ * 2);

  auto mk = [&](int kind, int base) {
    AuxArgs a;
    a.wq = wq; a.wk = wk; a.wv = wv; a.wo = wo; a.w1 = w1; a.w2 = w2;
    a.emb = emb; a.bq = bq; a.bk = bk; a.bv = bv;
    a.wqkv_t = wqkv_t; a.wo_t = wo_t; a.w1_t = w1_t; a.w2_t = w2_t;
    a.emb_bf = emb_bf; a.bqkv = bqkv;
    a.kind = kind; a.base = base;
    return a;
  };
  AuxArgs auxNone = mk(-1, 0);

  embed_k<<<M_, 256, 0, stream>>>(ids, emb, pos, x);

  for (int l = 0; l < L_; l++) {
    if (l == 0) {
      rmsnorm_k<<<2048 + 8216, 256, 0, stream>>>(x, n1w, hbuf, mk(0, 0), 2048);
      gemm_l2<64, 64, 0><<<1536 + 8192, 256, 0, stream>>>(
          hbuf, wqkv_t, bqkv, nullptr, qkv, nullptr,
          3072, 1024, 31, 5, mk(1, 0), 1536);
      attn_swa<<<512 + 10667, 256, 0, stream>>>(qkv, obuf, mk(3, 0), 512);
      gemm_l2<64, 64, 2><<<512 + 10667, 256, 0, stream>>>(
          obuf, wo_t, bo, x, nullptr, nullptr,
          1024, 1024, 31, 5, mk(3, 10667), 512);
      rmsnorm_k<<<2048 + 8192, 256, 0, stream>>>(x, n2w, hbuf, mk(2, 0), 2048);
      gemm_l2<64, 128, 1><<<1024, 256, 0, stream>>>(
          hbuf, w1_t, b1, nullptr, ff, nullptr,
          4096, 1024, 31, 5, auxNone, 1024);
      gemm_l2<64, 64, 2><<<512 + 10666, 256, 0, stream>>>(
          ff, w2_t, b2, x, nullptr, nullptr,
          1024, 4096, 31, 5, mk(3, 21334), 512);
    } else {
      rmsnorm_k<<<2048, 256, 0, stream>>>(x, n1w + l * D_, hbuf, auxNone, 2048);
      gemm_l2<64, 64, 0><<<1536, 256, 0, stream>>>(
          hbuf, wqkv_t + (size_t)l * 3 * 1024 * 1024, bqkv + l * 3072,
          nullptr, qkv, nullptr, 3072, 1024, 31, 5, auxNone, 1536);
      attn_swa<<<512, 256, 0, stream>>>(qkv, obuf, auxNone, 512);
      gemm_l2<64, 64, 2><<<512, 256, 0, stream>>>(
          obuf, wo_t + (size_t)l * 1024 * 1024, bo + l * D_,
          x, nullptr, nullptr, 1024, 1024, 31, 5, auxNone, 512);
      rmsnorm_k<<<2048, 256, 0, stream>>>(x, n2w + l * D_, hbuf, auxNone, 2048);
      gemm_l2<64, 128, 1><<<1024, 256, 0, stream>>>(
          hbuf, w1_t + (size_t)l * 4096 * 1024, b1 + l * DFF_,
          nullptr, ff, nullptr, 4096, 1024, 31, 5, auxNone, 1024);
      gemm_l2<64, 64, 2><<<512, 256, 0, stream>>>(
          ff, w2_t + (size_t)l * 1024 * 4096, b2 + l * D_,
          x, nullptr, nullptr, 1024, 4096, 31, 5, auxNone, 512);
    }
  }
  rmsnorm_k<<<2048, 256, 0, stream>>>(x, nfw, hbuf, auxNone, 2048);
  gemm_lmA<<<dim3(8 * (V_ / 256)), 512, 0, stream>>>(
      hbuf, emb_bf, (float*)d_out, V_);
}

// Round 20
// 538.520 us; speedup vs baseline: 1.0743x; 1.0743x over previous
//
#include <hip/hip_runtime.h>
#include <hip/hip_bf16.h>
#include <cstdint>

typedef __bf16 bf16;
typedef __bf16 bf16x8 __attribute__((ext_vector_type(8)));
typedef __bf16 bf16x4 __attribute__((ext_vector_type(4)));
typedef float  f32x4  __attribute__((ext_vector_type(4)));

constexpr int V_    = 32000;
constexpr int SMAX_ = 1024;
constexpr int D_    = 1024;
constexpr int H_    = 16;
constexpr int L_    = 2;
constexpr int DFF_  = 4096;
constexpr int WIN_  = 256;
constexpr int B_    = 2;
constexpr int M_    = B_ * SMAX_; // 2048

#define SBAR0_() __builtin_amdgcn_sched_barrier(0)
#define HWBAR_() { __builtin_amdgcn_s_barrier(); SBAR0_(); }
#define LGKM0_() { asm volatile("s_waitcnt lgkmcnt(0)" ::: "memory"); SBAR0_(); }
#define VM0_()   { asm volatile("s_waitcnt vmcnt(0)" ::: "memory"); SBAR0_(); }
#define VM8_()   { asm volatile("s_waitcnt vmcnt(8)" ::: "memory"); SBAR0_(); }

// ---------------------------------------------------------------------------
// Aux work: prep chunks attached as extra grid blocks to underfilled
// dispatches (R17/R18, passing). kind: -1 none, 0 qkv/wo transposes + pack,
// 1 w1 transpose, 2 w2 transpose, 3 emb f32->bf16 rows [base, base+count).
// ---------------------------------------------------------------------------
struct AuxArgs {
  const float *wq, *wk, *wv, *wo, *w1, *w2, *emb, *bq, *bk, *bv;
  bf16 *wqkv_t, *wo_t, *w1_t, *w2_t, *emb_bf;
  float *bqkv;
  int kind;
  int base;
};

__device__ __forceinline__ void aux_transpose(
    const float* src, bf16* dst, int Kk, int Nn, int tid, int t)
{
  __shared__ float tile[32][33];
  const int tx = t & 31, ty = t >> 5;
  int tilesX = Nn >> 5;
  int n0 = (tid % tilesX) << 5, k0 = (tid / tilesX) << 5;
  #pragma unroll
  for (int i = 0; i < 4; i++)
    tile[ty + i * 8][tx] = src[(long)(k0 + ty + i * 8) * Nn + n0 + tx];
  __syncthreads();
  #pragma unroll
  for (int i = 0; i < 4; i++)
    dst[(long)(n0 + ty + i * 8) * Kk + k0 + tx] = (bf16)tile[tx][ty + i * 8];
}

__device__ __forceinline__ void aux_do(const AuxArgs& A, int b, int t)
{
  if (A.kind == 0) {
    if (b < 8192) {                 // wq/wk/wv/wo: 4 mats x 2L x 1024 tiles
      int mat = b >> 11, r = b & 2047, z = r >> 10, tid = r & 1023;
      const float* s; bf16* d;
      if (mat == 0)      { s = A.wq + (long)z * 1048576; d = A.wqkv_t + (long)z * 3145728; }
      else if (mat == 1) { s = A.wk + (long)z * 1048576; d = A.wqkv_t + (long)z * 3145728 + 1048576; }
      else if (mat == 2) { s = A.wv + (long)z * 1048576; d = A.wqkv_t + (long)z * 3145728 + 2097152; }
      else               { s = A.wo + (long)z * 1048576; d = A.wo_t   + (long)z * 1048576; }
      aux_transpose(s, d, 1024, 1024, tid, t);
    } else {                        // pack bqkv (24 blocks)
      int i = (b - 8192) * 256 + t;
      if (i < L_ * 3072) {
        int l = i / 3072, c = i % 3072;
        float v = (c < 1024) ? A.bq[l * 1024 + c]
                : (c < 2048) ? A.bk[l * 1024 + c - 1024]
                             : A.bv[l * 1024 + c - 2048];
        A.bqkv[i] = v;
      }
    }
  } else if (A.kind == 1) {         // w1: 2L x 4096 tiles
    int z = b >> 12, tid = b & 4095;
    aux_transpose(A.w1 + (long)z * 4194304, A.w1_t + (long)z * 4194304, 1024, 4096, tid, t);
  } else if (A.kind == 2) {         // w2: 2L x 4096 tiles
    int z = b >> 12, tid = b & 4095;
    aux_transpose(A.w2 + (long)z * 4194304, A.w2_t + (long)z * 4194304, 4096, 1024, tid, t);
  } else if (A.kind == 3) {         // emb cvt rows
    long i = (long)(A.base + b) * 256 + t;
    float4 v = ((const float4*)A.emb)[i];
    bf16x4 o; o[0] = (bf16)v.x; o[1] = (bf16)v.y; o[2] = (bf16)v.z; o[3] = (bf16)v.w;
    ((bf16x4*)A.emb_bf)[i] = o;
  }
}

// ---------------------------------------------------------------------------
// LM head (R15-18, passing): 256x256, 8 waves (2Mx4N, wave 128x64), BK=32,
// 4 LDS buffers, depth-3 counted pipeline (vmcnt(8), one barrier/iter,
// 32 MFMA per sync), swapped-operand MFMA, f32x4 temporal epilogue.
// ---------------------------------------------------------------------------
__global__ __launch_bounds__(512, 1) void gemm_lmA(
    const bf16* __restrict__ A, const bf16* __restrict__ BT,
    float* __restrict__ outf, int Nn)
{
  constexpr int KK = 1024, NT = KK / 32;
  __shared__ __align__(16) bf16 ldsA[4 * 8192];   // 4 bufs x 256 rows x 32
  __shared__ __align__(16) bf16 ldsB[4 * 8192];

  const int t = threadIdx.x, lane = t & 63, w = t >> 6;
  const int l16 = lane & 15, lh = lane >> 4;
  const int wm = w >> 2, wn = w & 3;              // 2M x 4N, wave 128x64

  const int nloc = gridDim.x >> 3;                // 1000/8 = 125
  const int wg = (blockIdx.x & 7) * nloc + (blockIdx.x >> 3);
  const long m0 = (long)(wg & 7) * 256;
  const long n0 = (long)(wg >> 3) * 256;

  auto STG = [&](const bf16* src, long rowBase, bf16* dst, int k0) {
    #pragma unroll
    for (int j = 0; j < 2; ++j) {
      int p = j * 8192 + t * 16;
      int row = p >> 6;
      int sl = ((p >> 4) & 3) ^ (row & 3);
      const bf16* g = src + (rowBase + row) * (long)KK + k0 + sl * 8;
      __builtin_amdgcn_global_load_lds(
          (const __attribute__((address_space(1))) uint32_t*)g,
          (__attribute__((address_space(3))) uint32_t*)(dst + j * 4096 + w * 512),
          16, 0, 0);
    }
  };
  auto LDF = [&](const bf16* base, int rowb) -> bf16x8 {
    int row = rowb + l16;
    return *(const bf16x8*)(base + row * 32 + ((lh ^ (l16 & 3)) << 3));
  };

  f32x4 acc[8][4] = {};

  STG(A, m0, ldsA,          0);  STG(BT, n0, ldsB,          0);
  STG(A, m0, ldsA + 8192,  32);  STG(BT, n0, ldsB + 8192,  32);
  STG(A, m0, ldsA + 16384, 64);  STG(BT, n0, ldsB + 16384, 64);
  int kNext = 96;

  for (int i = 0; i < NT; ++i) {
    const int cur = i & 3, nb = (i + 3) & 3;
    VM8_();
    HWBAR_();
    const bf16* Ac = ldsA + cur * 8192;
    const bf16* Bc = ldsB + cur * 8192;
    bf16x8 af[8], bb[4];
    #pragma unroll
    for (int mi = 0; mi < 8; ++mi) af[mi] = LDF(Ac, wm * 128 + mi * 16);
    #pragma unroll
    for (int ni = 0; ni < 4; ++ni) bb[ni] = LDF(Bc, wn * 64 + ni * 16);
    STG(A, m0, ldsA + nb * 8192, kNext);
    STG(BT, n0, ldsB + nb * 8192, kNext);
    kNext += 32; if (kNext == KK) kNext = 0;
    LGKM0_();
    __builtin_amdgcn_s_setprio(1);
    #pragma unroll
    for (int mi = 0; mi < 8; ++mi)
      #pragma unroll
      for (int ni = 0; ni < 4; ++ni)
        acc[mi][ni] = __builtin_amdgcn_mfma_f32_16x16x32_bf16(bb[ni], af[mi], acc[mi][ni], 0, 0, 0);
    __builtin_amdgcn_s_setprio(0);
  }

  asm volatile("s_waitcnt vmcnt(0) lgkmcnt(0)" ::: "memory");
  #pragma unroll
  for (int mi = 0; mi < 8; ++mi) {
    long row = m0 + wm * 128 + mi * 16 + l16;
    #pragma unroll
    for (int ni = 0; ni < 4; ++ni) {
      long col = n0 + wn * 64 + ni * 16 + lh * 4;
      *(f32x4*)(outf + row * Nn + col) = acc[mi][ni];
    }
  }
}

// ---------------------------------------------------------------------------
// Layer GEMMs (R18 template, passing): BM/BN-templated, drain sync,
// swapped-operand MFMA, vectorized epilogues, optional aux tail.
// EPI: 0 bias->bf16, 1 bias+gelu->bf16, 2 bias+residual->f32, 3 ->f32
// ---------------------------------------------------------------------------
template<int BM, int BN, int EPI>
__global__ __launch_bounds__(256) void gemm_l2(
    const bf16* __restrict__ A, const bf16* __restrict__ BT,
    const float* __restrict__ bias, float* __restrict__ resid,
    bf16* __restrict__ outb, float* __restrict__ outf,
    int Nn, int Kk, int nbyMask, int nbyShift,
    AuxArgs aux, int mainBlocks)
{
  if ((int)blockIdx.x >= mainBlocks) {
    aux_do(aux, (int)blockIdx.x - mainBlocks, threadIdx.x);
    return;
  }
  constexpr int MR = BM / 32;
  constexpr int NR = BN / 32;
  constexpr int CA = BM / 32;
  constexpr int CB = BN / 32;
  __shared__ __align__(16) bf16 ldsA[2][BM * 64];
  __shared__ __align__(16) bf16 ldsB[2][BN * 64];

  const int t = threadIdx.x, lane = t & 63, w = t >> 6;
  const int l16 = lane & 15, lh = lane >> 4;
  const int wm = w >> 1, wn = w & 1;

  const int nwg = mainBlocks, bid = blockIdx.x;
  const int nloc = nwg >> 3;
  const int wg = (bid & 7) * nloc + (bid >> 3);
  const long m0 = (long)(wg & nbyMask) * BM;
  const long n0 = (long)(wg >> nbyShift) * BN;

  auto STGA = [&](int c, int k0) {
    #pragma unroll
    for (int q = 0; q < CA; ++q) {
      int row = q * 32 + (t >> 3);
      int sl  = (t & 7) ^ (row & 7);
      const bf16* g = A + (m0 + row) * (long)Kk + k0 + sl * 8;
      __builtin_amdgcn_global_load_lds(
          (const __attribute__((address_space(1))) uint32_t*)g,
          (__attribute__((address_space(3))) uint32_t*)(&ldsA[c][q * 2048 + t * 8]),
          16, 0, 0);
    }
  };
  auto STGB = [&](int c, int k0) {
    #pragma unroll
    for (int q = 0; q < CB; ++q) {
      int row = q * 32 + (t >> 3);
      int sl  = (t & 7) ^ (row & 7);
      const bf16* g = BT + (n0 + row) * (long)Kk + k0 + sl * 8;
      __builtin_amdgcn_global_load_lds(
          (const __attribute__((address_space(1))) uint32_t*)g,
          (__attribute__((address_space(3))) uint32_t*)(&ldsB[c][q * 2048 + t * 8]),
          16, 0, 0);
    }
  };
  auto LDA = [&](int c, int mi, int ks) -> bf16x8 {
    int row = wm * (BM / 2) + mi * 16 + l16;
    int sl  = (ks * 4 + lh) ^ (row & 7);
    return *(const bf16x8*)(&ldsA[c][row * 64 + sl * 8]);
  };
  auto LDB = [&](int c, int ni, int ks) -> bf16x8 {
    int row = wn * (BN / 2) + ni * 16 + l16;
    int sl  = (ks * 4 + lh) ^ (row & 7);
    return *(const bf16x8*)(&ldsB[c][row * 64 + sl * 8]);
  };

  f32x4 acc[MR][NR] = {};
  bf16x8 a[MR], b[NR];

  STGA(0, 0); STGB(0, 0);
  int kNext = 64;

  const int NT = Kk >> 6;
  for (int j = 0; j < NT; ++j) {
    const int c = j & 1;
    VM0_();
    HWBAR_();
    #pragma unroll
    for (int mi = 0; mi < MR; ++mi) a[mi] = LDA(c, mi, 0);
    #pragma unroll
    for (int ni = 0; ni < NR; ++ni) b[ni] = LDB(c, ni, 0);
    STGA(c ^ 1, kNext); STGB(c ^ 1, kNext);
    LGKM0_();
    __builtin_amdgcn_s_setprio(1);
    #pragma unroll
    for (int mi = 0; mi < MR; ++mi)
      #pragma unroll
      for (int ni = 0; ni < NR; ++ni)
        acc[mi][ni] = __builtin_amdgcn_mfma_f32_16x16x32_bf16(b[ni], a[mi], acc[mi][ni], 0, 0, 0);
    __builtin_amdgcn_s_setprio(0);
    HWBAR_();
    #pragma unroll
    for (int mi = 0; mi < MR; ++mi) a[mi] = LDA(c, mi, 1);
    #pragma unroll
    for (int ni = 0; ni < NR; ++ni) b[ni] = LDB(c, ni, 1);
    LGKM0_();
    __builtin_amdgcn_s_setprio(1);
    #pragma unroll
    for (int mi = 0; mi < MR; ++mi)
      #pragma unroll
      for (int ni = 0; ni < NR; ++ni)
        acc[mi][ni] = __builtin_amdgcn_mfma_f32_16x16x32_bf16(b[ni], a[mi], acc[mi][ni], 0, 0, 0);
    __builtin_amdgcn_s_setprio(0);
    kNext += 64; if (kNext == Kk) kNext = 0;
  }

  // swapped D: row = m (lane&15), col = n (lh*4 + reg)
  #pragma unroll
  for (int mi = 0; mi < MR; ++mi) {
    long row = m0 + wm * (BM / 2) + mi * 16 + l16;
    #pragma unroll
    for (int ni = 0; ni < NR; ++ni) {
      long col = n0 + wn * (BN / 2) + ni * 16 + lh * 4;
      f32x4 v = acc[mi][ni];
      if (EPI == 3) {
        *(f32x4*)(outf + row * Nn + col) = v;
      } else {
        f32x4 bv = *(const f32x4*)(bias + col);
        v += bv;
        if (EPI == 0) {
          bf16x4 o;
          #pragma unroll
          for (int e = 0; e < 4; ++e) o[e] = (bf16)v[e];
          *(bf16x4*)(outb + row * Nn + col) = o;
        } else if (EPI == 1) {
          bf16x4 o;
          #pragma unroll
          for (int e = 0; e < 4; ++e) {
            float xx = v[e];
            o[e] = (bf16)(0.5f * xx * (1.0f + erff(xx * 0.70710678118654752f)));
          }
          *(bf16x4*)(outb + row * Nn + col) = o;
        } else { // EPI == 2
          f32x4 r = *(f32x4*)(resid + row * Nn + col);
          r += v;
          *(f32x4*)(resid + row * Nn + col) = r;
        }
      }
    }
  }
}

// ---------------------------------------------------------------------------
// Sliding-window causal flash attention (passing) + optional aux tail.
// ---------------------------------------------------------------------------
__global__ __launch_bounds__(256) void attn_swa(
    const bf16* __restrict__ qkv, bf16* __restrict__ o,
    AuxArgs aux, int mainBlocks)
{
  if ((int)blockIdx.x >= mainBlocks) {
    aux_do(aux, (int)blockIdx.x - mainBlocks, threadIdx.x);
    return;
  }
  constexpr int PADK = 72;
  constexpr int PADV = 40;
  __shared__ bf16 Qs[64 * PADK];
  __shared__ bf16 Ks[32 * PADK];
  __shared__ bf16 Vt[64 * PADV];
  __shared__ bf16 Ps[4][16 * PADV];

  const int bid = blockIdx.x;
  const int qb = bid & 15;
  const int h  = (bid >> 4) & 15;
  const int b  = bid >> 8;
  const int q0 = qb * 64;
  const int t = threadIdx.x, lane = t & 63, w = t >> 6;
  const int l16 = lane & 15, lh = lane >> 4;

  #pragma unroll
  for (int i = 0; i < 2; i++) {
    int e = t + i * 256;
    int row = e >> 3, cc = e & 7;
    uint4 g = *(const uint4*)(qkv + ((long)(b * SMAX_ + q0 + row)) * 3072 + h * 64 + cc * 8);
    *(uint4*)(Qs + row * PADK + cc * 8) = g;
  }
  __syncthreads();
  bf16x8 aq[2];
  const int qrow = w * 16 + l16;
  #pragma unroll
  for (int ks = 0; ks < 2; ks++)
    aq[ks] = *(const bf16x8*)(Qs + qrow * PADK + ks * 32 + lh * 8);

  float m_run[4], l_run[4];
  f32x4 oacc[4];
  #pragma unroll
  for (int rr = 0; rr < 4; rr++) { m_run[rr] = -1e30f; l_run[rr] = 0.0f; }
  #pragma unroll
  for (int n = 0; n < 4; n++) oacc[n] = (f32x4){0.f, 0.f, 0.f, 0.f};

  const int tlo = q0 - (WIN_ - 1);
  const int jlo = (tlo <= 0) ? 0 : (tlo & ~31);
  const int iq  = q0 + w * 16 + lh * 4;

  for (int j0 = jlo; j0 < q0 + 64; j0 += 32) {
    __syncthreads();
    {
      int row = t >> 3, cc = t & 7;
      long base = ((long)(b * SMAX_ + j0 + row)) * 3072 + h * 64 + cc * 8;
      uint4 gk = *(const uint4*)(qkv + base + 1024);
      *(uint4*)(Ks + row * PADK + cc * 8) = gk;
      bf16x8 vv = *(const bf16x8*)(qkv + base + 2048);
      #pragma unroll
      for (int j = 0; j < 8; j++)
        Vt[(cc * 8 + j) * PADV + row] = vv[j];
    }
    __syncthreads();

    f32x4 s[2] = {(f32x4){0.f,0.f,0.f,0.f}, (f32x4){0.f,0.f,0.f,0.f}};
    #pragma unroll
    for (int nt = 0; nt < 2; nt++)
      #pragma unroll
      for (int ks = 0; ks < 2; ks++) {
        bf16x8 bk = *(const bf16x8*)(Ks + (nt * 16 + l16) * PADK + ks * 32 + lh * 8);
        s[nt] = __builtin_amdgcn_mfma_f32_16x16x32_bf16(aq[ks], bk, s[nt], 0, 0, 0);
      }

    float sc[2][4];
    #pragma unroll
    for (int nt = 0; nt < 2; nt++)
      #pragma unroll
      for (int rr = 0; rr < 4; rr++) {
        int i = iq + rr;
        int j = j0 + nt * 16 + l16;
        float v = s[nt][rr] * 0.125f;
        bool ok = (j <= i) && (i - j < WIN_);
        sc[nt][rr] = ok ? v : -1e30f;
      }

    float pb[2][4], alpha[4];
    #pragma unroll
    for (int rr = 0; rr < 4; rr++) {
      float mt = fmaxf(sc[0][rr], sc[1][rr]);
      #pragma unroll
      for (int off = 1; off < 16; off <<= 1) mt = fmaxf(mt, __shfl_xor(mt, off, 64));
      float mn = fmaxf(m_run[rr], mt);
      float a = __expf(m_run[rr] - mn);
      m_run[rr] = mn; alpha[rr] = a;
      float p0 = __expf(sc[0][rr] - mn);
      float p1 = __expf(sc[1][rr] - mn);
      pb[0][rr] = p0; pb[1][rr] = p1;
      float ls = p0 + p1;
      #pragma unroll
      for (int off = 1; off < 16; off <<= 1) ls += __shfl_xor(ls, off, 64);
      l_run[rr] = l_run[rr] * a + ls;
    }
    #pragma unroll
    for (int n = 0; n < 4; n++)
      #pragma unroll
      for (int rr = 0; rr < 4; rr++) oacc[n][rr] *= alpha[rr];

    #pragma unroll
    for (int rr = 0; rr < 4; rr++) {
      int prow = lh * 4 + rr;
      Ps[w][prow * PADV + l16]      = (bf16)pb[0][rr];
      Ps[w][prow * PADV + 16 + l16] = (bf16)pb[1][rr];
    }
    __syncthreads();

    bf16x8 pa = *(const bf16x8*)(&Ps[w][l16 * PADV + lh * 8]);
    #pragma unroll
    for (int n = 0; n < 4; n++) {
      bf16x8 bv = *(const bf16x8*)(Vt + (n * 16 + l16) * PADV + lh * 8);
      oacc[n] = __builtin_amdgcn_mfma_f32_16x16x32_bf16(pa, bv, oacc[n], 0, 0, 0);
    }
  }

  #pragma unroll
  for (int rr = 0; rr < 4; rr++) {
    int i = iq + rr;
    float inv = 1.0f / l_run[rr];
    #pragma unroll
    for (int n = 0; n < 4; n++)
      o[((long)(b * SMAX_ + i)) * D_ + h * 64 + n * 16 + l16] = (bf16)(oacc[n][rr] * inv);
  }
}

// ---------------------------------------------------------------------------
__global__ __launch_bounds__(256) void embed_k(
    const int* __restrict__ ids, const float* __restrict__ emb,
    const float* __restrict__ pos, float* __restrict__ x)
{
  const int m = blockIdx.x, t = threadIdx.x;
  const int id = ids[m];
  const int s = m & (SMAX_ - 1);
  float4 e = ((const float4*)(emb + (long)id * D_))[t];
  float4 p = ((const float4*)(pos + (long)s * D_))[t];
  float4 rr; rr.x = e.x + p.x; rr.y = e.y + p.y; rr.z = e.z + p.z; rr.w = e.w + p.w;
  ((float4*)(x + (long)m * D_))[t] = rr;
}

__global__ __launch_bounds__(256) void rmsnorm_k(
    const float* __restrict__ x, const float* __restrict__ wgt,
    bf16* __restrict__ out, AuxArgs aux, int mainBlocks)
{
  if ((int)blockIdx.x >= mainBlocks) {
    aux_do(aux, (int)blockIdx.x - mainBlocks, threadIdx.x);
    return;
  }
  __shared__ float red[4];
  const int m = blockIdx.x, t = threadIdx.x;
  float4 v = ((const float4*)(x + (long)m * D_))[t];
  float ss = v.x * v.x + v.y * v.y + v.z * v.z + v.w * v.w;
  #pragma unroll
  for (int off = 1; off < 64; off <<= 1) ss += __shfl_xor(ss, off, 64);
  const int lane = t & 63, w = t >> 6;
  if (lane == 0) red[w] = ss;
  __syncthreads();
  float tot = red[0] + red[1] + red[2] + red[3];
  float rs = rsqrtf(tot * (1.0f / D_) + 1e-6f);
  float4 g = ((const float4*)wgt)[t];
  bf16x4 o;
  o[0] = (bf16)(v.x * rs * g.x); o[1] = (bf16)(v.y * rs * g.y);
  o[2] = (bf16)(v.z * rs * g.z); o[3] = (bf16)(v.w * rs * g.w);
  ((bf16x4*)(out + (long)m * D_))[t] = o;
}

// ---------------------------------------------------------------------------
extern "C" void kernel_launch(void* const* d_in, const int* in_sizes, int n_in,
                              void* d_out, int out_size, void* d_ws, size_t ws_size,
                              hipStream_t stream)
{
  const int*   ids = (const int*)d_in[0];
  const float* emb = (const float*)d_in[1];
  const float* pos = (const float*)d_in[2];
  const float* n1w = (const float*)d_in[3];
  const float* n2w = (const float*)d_in[4];
  const float* wq  = (const float*)d_in[5];
  const float* bq  = (const float*)d_in[6];
  const float* wk  = (const float*)d_in[7];
  const float* bk  = (const float*)d_in[8];
  const float* wv  = (const float*)d_in[9];
  const float* bv  = (const float*)d_in[10];
  const float* wo  = (const float*)d_in[11];
  const float* bo  = (const float*)d_in[12];
  const float* w1  = (const float*)d_in[13];
  const float* b1  = (const float*)d_in[14];
  const float* w2  = (const float*)d_in[15];
  const float* b2  = (const float*)d_in[16];
  const float* nfw = (const float*)d_in[17];

  char* p = (char*)d_ws;
  auto alloc = [&](size_t bytes) {
    char* rr = p; p += (bytes + 255) & ~(size_t)255; return rr;
  };
  bf16*  wqkv_t = (bf16*) alloc((size_t)L_ * 3 * 1024 * 1024 * 2);
  bf16*  wo_t   = (bf16*) alloc((size_t)L_ * 1024 * 1024 * 2);
  bf16*  w1_t   = (bf16*) alloc((size_t)L_ * 4096 * 1024 * 2);
  bf16*  w2_t   = (bf16*) alloc((size_t)L_ * 1024 * 4096 * 2);
  bf16*  emb_bf = (bf16*) alloc((size_t)V_ * D_ * 2);
  float* bqkv   = (float*)alloc((size_t)L_ * 3072 * 4);
  float* x      = (float*)alloc((size_t)M_ * D_ * 4);
  bf16*  hbuf   = (bf16*) alloc((size_t)M_ * D_ * 2);
  bf16*  qkv    = (bf16*) alloc((size_t)M_ * 3072 * 2);
  bf16*  obuf   = (bf16*) alloc((size_t)M_ * D_ * 2);
  bf16*  ff     = (bf16*) alloc((size_t)M_ * DFF_ * 2);

  auto mk = [&](int kind, int base) {
    AuxArgs a;
    a.wq = wq; a.wk = wk; a.wv = wv; a.wo = wo; a.w1 = w1; a.w2 = w2;
    a.emb = emb; a.bq = bq; a.bk = bk; a.bv = bv;
    a.wqkv_t = wqkv_t; a.wo_t = wo_t; a.w1_t = w1_t; a.w2_t = w2_t;
    a.emb_bf = emb_bf; a.bqkv = bqkv;
    a.kind = kind; a.base = base;
    return a;
  };
  AuxArgs auxNone = mk(-1, 0);

  embed_k<<<M_, 256, 0, stream>>>(ids, emb, pos, x);

  for (int l = 0; l < L_; l++) {
    if (l == 0) {
      rmsnorm_k<<<2048 + 8216, 256, 0, stream>>>(x, n1w, hbuf, mk(0, 0), 2048);
      gemm_l2<64, 128, 0><<<768 + 8192, 256, 0, stream>>>(
          hbuf, wqkv_t, bqkv, nullptr, qkv, nullptr,
          3072, 1024, 31, 5, mk(1, 0), 768);
      attn_swa<<<512 + 10667, 256, 0, stream>>>(qkv, obuf, mk(3, 0), 512);
      gemm_l2<64, 64, 2><<<512 + 10667, 256, 0, stream>>>(
          obuf, wo_t, bo, x, nullptr, nullptr,
          1024, 1024, 31, 5, mk(3, 10667), 512);
      rmsnorm_k<<<2048 + 8192, 256, 0, stream>>>(x, n2w, hbuf, mk(2, 0), 2048);
      gemm_l2<128, 128, 1><<<512, 256, 0, stream>>>(
          hbuf, w1_t, b1, nullptr, ff, nullptr,
          4096, 1024, 15, 4, auxNone, 512);
      gemm_l2<64, 64, 2><<<512 + 10666, 256, 0, stream>>>(
          ff, w2_t, b2, x, nullptr, nullptr,
          1024, 4096, 31, 5, mk(3, 21334), 512);
    } else {
      rmsnorm_k<<<2048, 256, 0, stream>>>(x, n1w + l * D_, hbuf, auxNone, 2048);
      gemm_l2<64, 128, 0><<<768, 256, 0, stream>>>(
          hbuf, wqkv_t + (size_t)l * 3 * 1024 * 1024, bqkv + l * 3072,
          nullptr, qkv, nullptr, 3072, 1024, 31, 5, auxNone, 768);
      attn_swa<<<512, 256, 0, stream>>>(qkv, obuf, auxNone, 512);
      gemm_l2<64, 64, 2><<<512, 256, 0, stream>>>(
          obuf, wo_t + (size_t)l * 1024 * 1024, bo + l * D_,
          x, nullptr, nullptr, 1024, 1024, 31, 5, auxNone, 512);
      rmsnorm_k<<<2048, 256, 0, stream>>>(x, n2w + l * D_, hbuf, auxNone, 2048);
      gemm_l2<128, 128, 1><<<512, 256, 0, stream>>>(
          hbuf, w1_t + (size_t)l * 4096 * 1024, b1 + l * DFF_,
          nullptr, ff, nullptr, 4096, 1024, 15, 4, auxNone, 512);
      gemm_l2<64, 64, 2><<<512, 256, 0, stream>>>(
          ff, w2_t + (size_t)l * 1024 * 4096, b2 + l * D_,
          x, nullptr, nullptr, 1024, 4096, 31, 5, auxNone, 512);
    }
  }
  rmsnorm_k<<<2048, 256, 0, stream>>>(x, nfw, hbuf, auxNone, 2048);
  gemm_lmA<<<dim3(8 * (V_ / 256)), 512, 0, stream>>>(
      hbuf, emb_bf, (float*)d_out, V_);
}